// Round 3
// baseline (381.380 us; speedup 1.0000x reference)
//
#include <hip/hip_runtime.h>
#include <hip/hip_bf16.h>

// GAT 2-layer. N=100000, L1: H=4,C=32 (HC=128), L2: H=1,C=32.
//
// R1: CSR gather instead of float-atomic scatter (1588 -> 826 us).
// R2: cooperative softmax via shfl broadcast (826 -> 734).
// R3: single-pass softmax, float4 loads, 8-deep unroll (734 -> 595).
// R4: atomic-free scatter; bf16 h payload; 16-deep unroll (595 -> 491).
// R5: both GEMMs -> bf16 MFMA 16x16x32, zero LDS/barriers (491 -> 443).
// R6: FAILED launch_bounds(256,8) -> scratch spills. Reverted.
// R7: gather1 = R4-exact body; gemm2 casts o1 fp32->bf16 in-register (~408).
// R8: two-phase 8-edge batches, hv[8] in flight, bf16 o1 (408 -> 363;
//     gather1 107 -> 75). Compiler kept VGPR at 48 -> only ~4-6 loads truly
//     in flight; VALU 33%, HBM 45% -> still latency-bound.
// R9: mean degree = 17 -> avg dst runs the 8-edge loop ~2x; batch-boundary
//     stalls dominate. Widen to ONE 16-edge batch (hv[16], 64 VGPR payload)
//     -> ~1.3 stalls/dst. Tail: guard the hv load issue (R8 issued 8
//     unguarded loads vs avg r=4 -> ~100 MB garbage fetch). Shfl stays
//     unguarded (source lanes always active). VGPR -> 65-128 bin: cap 16
//     waves/CU == measured achieved occupancy, so no occupancy loss.
// Self-loops are implicit: edge ids >= E map to (n,n).

typedef __bf16 bf16x8 __attribute__((ext_vector_type(8)));
typedef float f32x4 __attribute__((ext_vector_type(4)));

__device__ __forceinline__ float lrelu(float v) { return v >= 0.f ? v : 0.2f * v; }

__device__ __forceinline__ unsigned f2bf(float f) {   // RTNE f32->bf16 (finite inputs)
    unsigned u = __float_as_uint(f);
    return (u + 0x7FFFu + ((u >> 16) & 1u)) >> 16;
}

__device__ __forceinline__ bf16x8 as_bf16x8(uint4 u) {
    union { uint4 u; bf16x8 b; } c; c.u = u; return c.b;
}

__device__ __forceinline__ void bf16x8_fma(uint4 hv, float a, float* acc) {
    acc[0] = fmaf(a, __uint_as_float(hv.x << 16), acc[0]);
    acc[1] = fmaf(a, __uint_as_float(hv.x & 0xFFFF0000u), acc[1]);
    acc[2] = fmaf(a, __uint_as_float(hv.y << 16), acc[2]);
    acc[3] = fmaf(a, __uint_as_float(hv.y & 0xFFFF0000u), acc[3]);
    acc[4] = fmaf(a, __uint_as_float(hv.z << 16), acc[4]);
    acc[5] = fmaf(a, __uint_as_float(hv.z & 0xFFFF0000u), acc[5]);
    acc[6] = fmaf(a, __uint_as_float(hv.w << 16), acc[6]);
    acc[7] = fmaf(a, __uint_as_float(hv.w & 0xFFFF0000u), acc[7]);
}

// ---------------- weight cast: W1[128,128] -> w1t[c][k] bf16 ; W2 -> w2t[c][k]
__global__ __launch_bounds__(256) void cast_w_k(const float* __restrict__ W1,
                                                const float* __restrict__ W2,
                                                ushort* __restrict__ w1t,
                                                ushort* __restrict__ w2t) {
    int tid = blockIdx.x * 256 + threadIdx.x;
    if (tid < 16384) {
        int k = tid >> 7, c = tid & 127;
        w1t[c * 128 + k] = (ushort)f2bf(W1[tid]);
    }
    if (tid < 4096) {
        int k = tid >> 5, c = tid & 31;
        w2t[c * 128 + k] = (ushort)f2bf(W2[tid]);
    }
}

// ---------------- GEMM1 (MFMA): x[N,128]fp32 (cast in-reg) @ W1 -> h[N,128]bf16 + as/ad
// Block: 64 rows, 4 waves x 16 rows. 8 col-tiles, K=128 in 4 steps. No LDS.
__global__ __launch_bounds__(256) void gemm1_mfma(
    const float* __restrict__ x, const ushort* __restrict__ w1t,
    const float* __restrict__ atts, const float* __restrict__ attd,
    ushort* __restrict__ h, float* __restrict__ as_, float* __restrict__ ad_, int N) {
    const int w = threadIdx.x >> 6;
    const int l = threadIdx.x & 63;
    const int c15 = l & 15;
    const int quad = l >> 4;
    const int n_base = blockIdx.x * 64 + w * 16;
    const int n = n_base + c15;

    bf16x8 a[4];
    if (n < N) {
        const float4* xr = (const float4*)(x + (size_t)n * 128);
#pragma unroll
        for (int ks = 0; ks < 4; ks++) {
            float4 p0 = xr[ks * 8 + quad * 2];
            float4 p1 = xr[ks * 8 + quad * 2 + 1];
            uint4 u;
            u.x = f2bf(p0.x) | (f2bf(p0.y) << 16);
            u.y = f2bf(p0.z) | (f2bf(p0.w) << 16);
            u.z = f2bf(p1.x) | (f2bf(p1.y) << 16);
            u.w = f2bf(p1.z) | (f2bf(p1.w) << 16);
            a[ks] = as_bf16x8(u);
        }
    } else {
        uint4 z = make_uint4(0, 0, 0, 0);
#pragma unroll
        for (int ks = 0; ks < 4; ks++) a[ks] = as_bf16x8(z);
    }

    f32x4 acc[8];
#pragma unroll
    for (int ct = 0; ct < 8; ct++) acc[ct] = (f32x4){0.f, 0.f, 0.f, 0.f};

#pragma unroll
    for (int ct = 0; ct < 8; ct++) {
        const uint4* wr = (const uint4*)(w1t + (size_t)(ct * 16 + c15) * 128);
#pragma unroll
        for (int ks = 0; ks < 4; ks++) {
            bf16x8 bfrag = as_bf16x8(wr[ks * 4 + quad]);
            acc[ct] = __builtin_amdgcn_mfma_f32_16x16x32_bf16(a[ks], bfrag, acc[ct], 0, 0, 0);
        }
    }

    // h stores: lane holds col=ct*16+c15, rows n_base+quad*4+reg
#pragma unroll
    for (int ct = 0; ct < 8; ct++) {
        int col = ct * 16 + c15;
#pragma unroll
        for (int reg = 0; reg < 4; reg++) {
            int n_out = n_base + quad * 4 + reg;
            if (n_out < N) h[(size_t)n_out * 128 + col] = (ushort)f2bf(acc[ct][reg]);
        }
    }
    // attention logits per head (cols of head hh live in tiles 2hh, 2hh+1)
#pragma unroll
    for (int hh = 0; hh < 4; hh++) {
        float sA = atts[hh * 32 + c15], sB = atts[hh * 32 + 16 + c15];
        float dA = attd[hh * 32 + c15], dB = attd[hh * 32 + 16 + c15];
#pragma unroll
        for (int reg = 0; reg < 4; reg++) {
            float ps = acc[2 * hh][reg] * sA + acc[2 * hh + 1][reg] * sB;
            float pd = acc[2 * hh][reg] * dA + acc[2 * hh + 1][reg] * dB;
            ps += __shfl_xor(ps, 1); pd += __shfl_xor(pd, 1);
            ps += __shfl_xor(ps, 2); pd += __shfl_xor(pd, 2);
            ps += __shfl_xor(ps, 4); pd += __shfl_xor(pd, 4);
            ps += __shfl_xor(ps, 8); pd += __shfl_xor(pd, 8);
            int n_out = n_base + quad * 4 + reg;
            if (c15 == 0 && n_out < N) { as_[n_out * 4 + hh] = ps; ad_[n_out * 4 + hh] = pd; }
        }
    }
}

// ---------------- GEMM2 (MFMA): o1[N,128]bf16 @ W2 -> h2[N,32]bf16 + as/ad
__global__ __launch_bounds__(256) void gemm2_mfma(
    const ushort* __restrict__ ob, const ushort* __restrict__ w2t,
    const float* __restrict__ atts, const float* __restrict__ attd,
    ushort* __restrict__ h, float* __restrict__ as_, float* __restrict__ ad_, int N) {
    const int w = threadIdx.x >> 6;
    const int l = threadIdx.x & 63;
    const int c15 = l & 15;
    const int quad = l >> 4;
    const int n_base = blockIdx.x * 64 + w * 16;
    const int n = n_base + c15;

    bf16x8 a[4];
    if (n < N) {
        const uint4* xr = (const uint4*)(ob + (size_t)n * 128);
#pragma unroll
        for (int ks = 0; ks < 4; ks++) a[ks] = as_bf16x8(xr[ks * 4 + quad]);
    } else {
        uint4 z = make_uint4(0, 0, 0, 0);
#pragma unroll
        for (int ks = 0; ks < 4; ks++) a[ks] = as_bf16x8(z);
    }

    f32x4 acc[2];
#pragma unroll
    for (int ct = 0; ct < 2; ct++) acc[ct] = (f32x4){0.f, 0.f, 0.f, 0.f};

#pragma unroll
    for (int ct = 0; ct < 2; ct++) {
        const uint4* wr = (const uint4*)(w2t + (size_t)(ct * 16 + c15) * 128);
#pragma unroll
        for (int ks = 0; ks < 4; ks++) {
            bf16x8 bfrag = as_bf16x8(wr[ks * 4 + quad]);
            acc[ct] = __builtin_amdgcn_mfma_f32_16x16x32_bf16(a[ks], bfrag, acc[ct], 0, 0, 0);
        }
    }

#pragma unroll
    for (int ct = 0; ct < 2; ct++) {
        int col = ct * 16 + c15;
#pragma unroll
        for (int reg = 0; reg < 4; reg++) {
            int n_out = n_base + quad * 4 + reg;
            if (n_out < N) h[(size_t)n_out * 32 + col] = (ushort)f2bf(acc[ct][reg]);
        }
    }
    float sA = atts[c15], sB = atts[16 + c15];
    float dA = attd[c15], dB = attd[16 + c15];
#pragma unroll
    for (int reg = 0; reg < 4; reg++) {
        float ps = acc[0][reg] * sA + acc[1][reg] * sB;
        float pd = acc[0][reg] * dA + acc[1][reg] * dB;
        ps += __shfl_xor(ps, 1); pd += __shfl_xor(pd, 1);
        ps += __shfl_xor(ps, 2); pd += __shfl_xor(pd, 2);
        ps += __shfl_xor(ps, 4); pd += __shfl_xor(pd, 4);
        ps += __shfl_xor(ps, 8); pd += __shfl_xor(pd, 8);
        int n_out = n_base + quad * 4 + reg;
        if (c15 == 0 && n_out < N) { as_[n_out] = ps; ad_[n_out] = pd; }
    }
}

// ---------------- CSR build: hist+rank -> scan -> atomic-free scatter -------
__global__ __launch_bounds__(256) void hist_rank_k(const int* __restrict__ ei, int E, int N,
                                                   int* __restrict__ deg, int* __restrict__ rank) {
    int e = blockIdx.x * 256 + threadIdx.x;
    if (e >= E + N) return;
    int d = (e < E) ? ei[E + e] : e - E;
    rank[e] = atomicAdd(&deg[d], 1);
}

__global__ __launch_bounds__(256) void scan1_k(const int* __restrict__ deg,
                                               int* __restrict__ tmp, int* __restrict__ partial, int N) {
    __shared__ int sh[256];
    int i = blockIdx.x * 256 + threadIdx.x;
    int v = (i < N) ? deg[i] : 0;
    sh[threadIdx.x] = v;
    __syncthreads();
#pragma unroll
    for (int off = 1; off < 256; off <<= 1) {
        int t = (threadIdx.x >= off) ? sh[threadIdx.x - off] : 0;
        __syncthreads();
        sh[threadIdx.x] += t;
        __syncthreads();
    }
    if (i < N) tmp[i] = sh[threadIdx.x];
    if (threadIdx.x == 255) partial[blockIdx.x] = sh[255];
}

__global__ __launch_bounds__(1024) void scan2_k(int* __restrict__ partial, int B) {
    __shared__ int sh[1024];
    int i = threadIdx.x;
    int v = (i < B) ? partial[i] : 0;
    sh[i] = v;
    __syncthreads();
#pragma unroll
    for (int off = 1; off < 1024; off <<= 1) {
        int t = (i >= off) ? sh[i - off] : 0;
        __syncthreads();
        sh[i] += t;
        __syncthreads();
    }
    if (i < B) partial[i] = sh[i] - v;   // exclusive
}

__global__ __launch_bounds__(256) void scan3_k(const int* __restrict__ tmp, const int* __restrict__ partial,
                                               int* __restrict__ rs, int N) {
    int i = blockIdx.x * 256 + threadIdx.x;
    if (i < N) rs[i + 1] = tmp[i] + partial[blockIdx.x];
    if (i == 0) rs[0] = 0;
}

__global__ __launch_bounds__(256) void scatter_k(const int* __restrict__ ei, const int* __restrict__ rank,
                                                 const int* __restrict__ rs, int E, int N,
                                                 int* __restrict__ csr) {
    int e = blockIdx.x * 256 + threadIdx.x;
    if (e >= E + N) return;
    int s, d;
    if (e < E) { s = ei[e]; d = ei[E + e]; } else { s = e - E; d = s; }
    csr[rs[d] + rank[e]] = s;      // fire-and-forget random store
}

// ---------------- layer-1 gather (R9): 16 lanes/dst, 8 bf16 ch/lane.
// ONE 16-edge batch per loop iter (hv[16] = 64 VGPR of payload in flight);
// next batch's csr prefetched across the FMA phase. Tail: shfl unguarded
// (source lanes always active), hv LOAD issue guarded by (e < r) to avoid
// ~100 MB of garbage fetch R8's s=0 fallback caused.
__global__ __launch_bounds__(256) void gather1_k(
    const int* __restrict__ rs, const int* __restrict__ csr,
    const float* __restrict__ as_, const float* __restrict__ ad_,
    const uint4* __restrict__ h, const float* __restrict__ b,
    ushort* __restrict__ o, int N) {
    const int jj = threadIdx.x & 31;
    const int l16 = jj & 15;
    const int sub = jj & 16;             // 16-lane subgroup base in 32-window
    const int d = blockIdx.x * 16 + (threadIdx.x >> 5) * 2 + (jj >> 4);
    if (d >= N) return;
    const int hl = l16 >> 2;             // my head
    const int sl = l16 & 3;              // my slot base
    const int beg = rs[d], end = rs[d + 1];
    const float adv = ad_[d * 4 + hl];

    float acc[8];
#pragma unroll
    for (int i = 0; i < 8; i++) acc[i] = 0.f;
    float den = 0.f;

    int j0 = beg;
    int sv0 = 0, sv1 = 0, sv2 = 0, sv3 = 0;
    float ex0 = 0.f, ex1 = 0.f, ex2 = 0.f, ex3 = 0.f;
    bool have = (j0 + 16 <= end);
    if (have) {
        sv0 = csr[j0 + sl];      sv1 = csr[j0 + sl + 4];
        sv2 = csr[j0 + sl + 8];  sv3 = csr[j0 + sl + 12];
        ex0 = __expf(fminf(lrelu(as_[sv0 * 4 + hl] + adv), 80.f));
        ex1 = __expf(fminf(lrelu(as_[sv1 * 4 + hl] + adv), 80.f));
        ex2 = __expf(fminf(lrelu(as_[sv2 * 4 + hl] + adv), 80.f));
        ex3 = __expf(fminf(lrelu(as_[sv3 * 4 + hl] + adv), 80.f));
    }
    while (have) {
        bool nhave = (j0 + 32 <= end);
        int na = nhave ? (j0 + 16) : beg;        // safe addr (deg>=16 here)
        int p0 = csr[na + sl],     p1 = csr[na + sl + 4];
        int p2 = csr[na + sl + 8], p3 = csr[na + sl + 12];
        den += ex0 + ex1 + ex2 + ex3;
        float av[16]; uint4 hv[16];
#pragma unroll
        for (int e = 0; e < 16; e++) {
            const int k = e >> 2, q = e & 3;
            const int srcl = sub + (l16 & 12) + q;
            float exk = (k == 0) ? ex0 : (k == 1) ? ex1 : (k == 2) ? ex2 : ex3;
            int   svk = (k == 0) ? sv0 : (k == 1) ? sv1 : (k == 2) ? sv2 : sv3;
            av[e] = __shfl(exk, srcl, 32);
            int s = __shfl(svk, srcl, 32);
            hv[e] = h[(size_t)s * 16 + l16];
        }
        // next-batch as_ + exp: issued after hv so their wait leaves hv in flight
        float q0 = __expf(fminf(lrelu(as_[p0 * 4 + hl] + adv), 80.f));
        float q1 = __expf(fminf(lrelu(as_[p1 * 4 + hl] + adv), 80.f));
        float q2 = __expf(fminf(lrelu(as_[p2 * 4 + hl] + adv), 80.f));
        float q3 = __expf(fminf(lrelu(as_[p3 * 4 + hl] + adv), 80.f));
#pragma unroll
        for (int e = 0; e < 16; e++) bf16x8_fma(hv[e], av[e], acc);
        sv0 = p0; sv1 = p1; sv2 = p2; sv3 = p3;
        ex0 = q0; ex1 = q1; ex2 = q2; ex3 = q3;
        j0 += 16; have = nhave;
    }
    int r = end - j0;                    // 0..15
    if (r > 0) {
        float e0 = 0.f, e1 = 0.f, e2 = 0.f, e3 = 0.f;
        int   s0 = 0,   s1 = 0,   s2 = 0,   s3 = 0;
        if (sl < r) {
            s0 = csr[j0 + sl];
            e0 = __expf(fminf(lrelu(as_[s0 * 4 + hl] + adv), 80.f));
            den += e0;
        }
        if (sl + 4 < r) {
            s1 = csr[j0 + sl + 4];
            e1 = __expf(fminf(lrelu(as_[s1 * 4 + hl] + adv), 80.f));
            den += e1;
        }
        if (sl + 8 < r) {
            s2 = csr[j0 + sl + 8];
            e2 = __expf(fminf(lrelu(as_[s2 * 4 + hl] + adv), 80.f));
            den += e2;
        }
        if (sl + 12 < r) {
            s3 = csr[j0 + sl + 12];
            e3 = __expf(fminf(lrelu(as_[s3 * 4 + hl] + adv), 80.f));
            den += e3;
        }
        float av[16]; uint4 hv[16];
#pragma unroll
        for (int e = 0; e < 16; e++) {
            const int k = e >> 2, q = e & 3;
            const int srcl = sub + (l16 & 12) + q;
            float exk = (k == 0) ? e0 : (k == 1) ? e1 : (k == 2) ? e2 : e3;
            int   svk = (k == 0) ? s0 : (k == 1) ? s1 : (k == 2) ? s2 : s3;
            av[e] = __shfl(exk, srcl, 32);             // unguarded: src lanes active
            int s = __shfl(svk, srcl, 32);
            if (e < r) hv[e] = h[(size_t)s * 16 + l16]; // guarded: no garbage fetch
        }
#pragma unroll
        for (int e = 0; e < 16; e++) if (e < r) bf16x8_fma(hv[e], av[e], acc);
    }
    den += __shfl_xor(den, 1, 32);
    den += __shfl_xor(den, 2, 32);
    const float rcp = 1.f / (den + 1e-16f);
    float4 b0 = *(const float4*)&b[l16 * 8];
    float4 b1 = *(const float4*)&b[l16 * 8 + 4];
    float v0 = fmaxf(acc[0] * rcp + b0.x, 0.f);
    float v1 = fmaxf(acc[1] * rcp + b0.y, 0.f);
    float v2 = fmaxf(acc[2] * rcp + b0.z, 0.f);
    float v3 = fmaxf(acc[3] * rcp + b0.w, 0.f);
    float v4 = fmaxf(acc[4] * rcp + b1.x, 0.f);
    float v5 = fmaxf(acc[5] * rcp + b1.y, 0.f);
    float v6 = fmaxf(acc[6] * rcp + b1.z, 0.f);
    float v7 = fmaxf(acc[7] * rcp + b1.w, 0.f);
    uint4 pk;
    pk.x = f2bf(v0) | (f2bf(v1) << 16);
    pk.y = f2bf(v2) | (f2bf(v3) << 16);
    pk.z = f2bf(v4) | (f2bf(v5) << 16);
    pk.w = f2bf(v6) | (f2bf(v7) << 16);
    ((uint4*)o)[(size_t)d * 16 + l16] = pk;
}

// ---------------- layer-2 gather (R9): 4 lanes/dst, one 16-edge batch/iter.
__global__ __launch_bounds__(256) void gather2_k(
    const int* __restrict__ rs, const int* __restrict__ csr,
    const float* __restrict__ as_, const float* __restrict__ ad_,
    const uint4* __restrict__ h, const float* __restrict__ b,
    float* __restrict__ o, int N) {
    const int jj = threadIdx.x & 31;
    const int l4 = jj & 3;
    const int sub = jj & 28;             // 4-lane subgroup base
    const int d = blockIdx.x * 64 + (threadIdx.x >> 5) * 8 + (jj >> 2);
    if (d >= N) return;
    const int beg = rs[d], end = rs[d + 1];
    const float adv = ad_[d];

    float acc[8];
#pragma unroll
    for (int i = 0; i < 8; i++) acc[i] = 0.f;
    float den = 0.f;

    int j0 = beg;
    int sv0 = 0, sv1 = 0, sv2 = 0, sv3 = 0;
    float ex0 = 0.f, ex1 = 0.f, ex2 = 0.f, ex3 = 0.f;
    bool have = (j0 + 16 <= end);
    if (have) {
        sv0 = csr[j0 + l4];      sv1 = csr[j0 + l4 + 4];
        sv2 = csr[j0 + l4 + 8];  sv3 = csr[j0 + l4 + 12];
        ex0 = __expf(fminf(lrelu(as_[sv0] + adv), 80.f));
        ex1 = __expf(fminf(lrelu(as_[sv1] + adv), 80.f));
        ex2 = __expf(fminf(lrelu(as_[sv2] + adv), 80.f));
        ex3 = __expf(fminf(lrelu(as_[sv3] + adv), 80.f));
    }
    while (have) {
        bool nhave = (j0 + 32 <= end);
        int na = nhave ? (j0 + 16) : beg;
        int p0 = csr[na + l4],     p1 = csr[na + l4 + 4];
        int p2 = csr[na + l4 + 8], p3 = csr[na + l4 + 12];
        den += ex0 + ex1 + ex2 + ex3;
        float av[16]; uint4 hv[16];
#pragma unroll
        for (int e = 0; e < 16; e++) {
            const int k = e >> 2, q = e & 3;
            const int srcl = sub + q;
            float exk = (k == 0) ? ex0 : (k == 1) ? ex1 : (k == 2) ? ex2 : ex3;
            int   svk = (k == 0) ? sv0 : (k == 1) ? sv1 : (k == 2) ? sv2 : sv3;
            av[e] = __shfl(exk, srcl, 32);
            int s = __shfl(svk, srcl, 32);
            hv[e] = h[(size_t)s * 4 + l4];
        }
        float q0 = __expf(fminf(lrelu(as_[p0] + adv), 80.f));
        float q1 = __expf(fminf(lrelu(as_[p1] + adv), 80.f));
        float q2 = __expf(fminf(lrelu(as_[p2] + adv), 80.f));
        float q3 = __expf(fminf(lrelu(as_[p3] + adv), 80.f));
#pragma unroll
        for (int e = 0; e < 16; e++) bf16x8_fma(hv[e], av[e], acc);
        sv0 = p0; sv1 = p1; sv2 = p2; sv3 = p3;
        ex0 = q0; ex1 = q1; ex2 = q2; ex3 = q3;
        j0 += 16; have = nhave;
    }
    int r = end - j0;                    // 0..15
    if (r > 0) {
        float e0 = 0.f, e1 = 0.f, e2 = 0.f, e3 = 0.f;
        int   s0 = 0,   s1 = 0,   s2 = 0,   s3 = 0;
        if (l4 < r) {
            s0 = csr[j0 + l4];
            e0 = __expf(fminf(lrelu(as_[s0] + adv), 80.f));
            den += e0;
        }
        if (l4 + 4 < r) {
            s1 = csr[j0 + l4 + 4];
            e1 = __expf(fminf(lrelu(as_[s1] + adv), 80.f));
            den += e1;
        }
        if (l4 + 8 < r) {
            s2 = csr[j0 + l4 + 8];
            e2 = __expf(fminf(lrelu(as_[s2] + adv), 80.f));
            den += e2;
        }
        if (l4 + 12 < r) {
            s3 = csr[j0 + l4 + 12];
            e3 = __expf(fminf(lrelu(as_[s3] + adv), 80.f));
            den += e3;
        }
        float av[16]; uint4 hv[16];
#pragma unroll
        for (int e = 0; e < 16; e++) {
            const int k = e >> 2, q = e & 3;
            const int srcl = sub + q;
            float exk = (k == 0) ? e0 : (k == 1) ? e1 : (k == 2) ? e2 : e3;
            int   svk = (k == 0) ? s0 : (k == 1) ? s1 : (k == 2) ? s2 : s3;
            av[e] = __shfl(exk, srcl, 32);             // unguarded
            int s = __shfl(svk, srcl, 32);
            if (e < r) hv[e] = h[(size_t)s * 4 + l4];  // guarded issue
        }
#pragma unroll
        for (int e = 0; e < 16; e++) if (e < r) bf16x8_fma(hv[e], av[e], acc);
    }
    den += __shfl_xor(den, 1, 32);
    den += __shfl_xor(den, 2, 32);
    const float rcp = 1.f / (den + 1e-16f);
    float4 b0 = *(const float4*)&b[l4 * 8];
    float4 b1 = *(const float4*)&b[l4 * 8 + 4];
    float4 o0, o1v;
    o0.x  = acc[0] * rcp + b0.x;
    o0.y  = acc[1] * rcp + b0.y;
    o0.z  = acc[2] * rcp + b0.z;
    o0.w  = acc[3] * rcp + b0.w;
    o1v.x = acc[4] * rcp + b1.x;
    o1v.y = acc[5] * rcp + b1.y;
    o1v.z = acc[6] * rcp + b1.z;
    o1v.w = acc[7] * rcp + b1.w;
    *(float4*)&o[(size_t)d * 32 + l4 * 8]     = o0;
    *(float4*)&o[(size_t)d * 32 + l4 * 8 + 4] = o1v;
}

extern "C" void kernel_launch(void* const* d_in, const int* in_sizes, int n_in,
                              void* d_out, int out_size, void* d_ws, size_t ws_size,
                              hipStream_t stream) {
    const float* x    = (const float*)d_in[0];
    const int*   ei   = (const int*)d_in[1];
    const float* W1   = (const float*)d_in[2];
    const float* as1v = (const float*)d_in[3];
    const float* ad1v = (const float*)d_in[4];
    const float* b1   = (const float*)d_in[5];
    const float* W2   = (const float*)d_in[6];
    const float* as2v = (const float*)d_in[7];
    const float* ad2v = (const float*)d_in[8];
    const float* b2   = (const float*)d_in[9];
    float* out = (float*)d_out;

    const int N = in_sizes[0] / 128;
    const int E = in_sizes[1] / 2;
    const int EN = E + N;
    const int B = (N + 255) / 256;   // scan chunks (must be <= 1024)

    // workspace layout
    char* base = (char*)d_ws;
    size_t o = 0;
    auto alloc = [&](size_t bytes) { void* p = base + o; o += (bytes + 255) & ~(size_t)255; return p; };
    ushort* w1t  = (ushort*)alloc((size_t)128 * 128 * 2);
    ushort* w2t  = (ushort*)alloc((size_t)32 * 128 * 2);
    ushort* h1   = (ushort*)alloc((size_t)N * 128 * 2);
    ushort* h2   = (ushort*)alloc((size_t)N * 32 * 2);
    ushort* o1   = (ushort*)alloc((size_t)N * 128 * 2);
    float*  as1  = (float*)alloc((size_t)N * 4 * 4);
    float*  ad1  = (float*)alloc((size_t)N * 4 * 4);
    float*  as2  = (float*)alloc((size_t)N * 4);
    float*  ad2  = (float*)alloc((size_t)N * 4);
    int*    deg  = (int*)alloc((size_t)N * 4);
    int*    tmp  = (int*)alloc((size_t)N * 4);
    int*    part = (int*)alloc((size_t)1024 * 4);
    int*    rs   = (int*)alloc((size_t)(N + 1) * 4);
    int*    rank = (int*)alloc((size_t)EN * 4);
    int*    csr  = (int*)alloc((size_t)EN * 4);

    hipMemsetAsync(deg, 0, (size_t)N * 4, stream);

    const int nbE = (EN + 255) / 256;
    const int nbN = (N + 255) / 256;
    const int nbG = (N + 63) / 64;

    // ---- weight cast + layer-1 GEMM (MFMA, fused x cast) + CSR build
    cast_w_k<<<64, 256, 0, stream>>>(W1, W2, w1t, w2t);
    gemm1_mfma<<<nbG, 256, 0, stream>>>(x, w1t, as1v, ad1v, h1, as1, ad1, N);
    hist_rank_k<<<nbE, 256, 0, stream>>>(ei, E, N, deg, rank);
    scan1_k<<<nbN, 256, 0, stream>>>(deg, tmp, part, N);
    scan2_k<<<1, 1024, 0, stream>>>(part, B);
    scan3_k<<<nbN, 256, 0, stream>>>(tmp, part, rs, N);
    scatter_k<<<nbE, 256, 0, stream>>>(ei, rank, rs, E, N, csr);

    // ---- layer 1 edge softmax + aggregate + bias + relu -> o1 (bf16)
    gather1_k<<<(N + 15) / 16, 256, 0, stream>>>(rs, csr, as1, ad1, (const uint4*)h1, b1, o1, N);

    // ---- layer 2
    gemm2_mfma<<<nbG, 256, 0, stream>>>(o1, w2t, as2v, ad2v, h2, as2, ad2, N);
    gather2_k<<<(N + 63) / 64, 256, 0, stream>>>(rs, csr, as2, ad2, (const uint4*)h2, b2, out, N);
}

// Round 4
// 378.427 us; speedup vs baseline: 1.0078x; 1.0078x over previous
//
#include <hip/hip_runtime.h>
#include <hip/hip_bf16.h>

// GAT 2-layer. N=100000, L1: H=4,C=32 (HC=128), L2: H=1,C=32.
//
// R1: CSR gather instead of float-atomic scatter (1588 -> 826 us).
// R2: cooperative softmax via shfl broadcast (826 -> 734).
// R3: single-pass softmax, float4 loads, 8-deep unroll (734 -> 595).
// R4: atomic-free scatter; bf16 h payload; 16-deep unroll (595 -> 491).
// R5: both GEMMs -> bf16 MFMA 16x16x32, zero LDS/barriers (491 -> 443).
// R6: FAILED launch_bounds(256,8) -> scratch spills. Reverted.
// R7: gather1 = R4-exact body; gemm2 casts o1 fp32->bf16 in-register (~408).
// R8: two-phase 8-edge batches, hv[8] in flight, bf16 o1 (408 -> 363;
//     gather1 107 -> 75; VGPR 48, occ 47.5%).
// R9: FAILED 16-edge batches via hv[16]: VGPR 84 -> occ 28%, gather1 83.7.
//     Lesson: registers are the scarce resource; TLP loss > MLP gain.
// R10: iteration-halving WITHOUT register cost: 2x lanes per dst. gather1:
//     32 lanes/dst, two 16-lane halves process edges [0-7]/[8-15] of a
//     16-edge batch, each half R8's exact hv[8] footprint. Per-dst stalls
//     ~1.6x fewer, wave count 2x, VGPR stays <=64 bin. Cross-half combine
//     (shfl_xor 16) in epilogue; half0 writes. gather2 same (4->8 lanes/dst,
//     halves load disjoint slot ranges). Tail keeps guarded load issue.
// Self-loops are implicit: edge ids >= E map to (n,n).

typedef __bf16 bf16x8 __attribute__((ext_vector_type(8)));
typedef float f32x4 __attribute__((ext_vector_type(4)));

__device__ __forceinline__ float lrelu(float v) { return v >= 0.f ? v : 0.2f * v; }

__device__ __forceinline__ unsigned f2bf(float f) {   // RTNE f32->bf16 (finite inputs)
    unsigned u = __float_as_uint(f);
    return (u + 0x7FFFu + ((u >> 16) & 1u)) >> 16;
}

__device__ __forceinline__ bf16x8 as_bf16x8(uint4 u) {
    union { uint4 u; bf16x8 b; } c; c.u = u; return c.b;
}

__device__ __forceinline__ void bf16x8_fma(uint4 hv, float a, float* acc) {
    acc[0] = fmaf(a, __uint_as_float(hv.x << 16), acc[0]);
    acc[1] = fmaf(a, __uint_as_float(hv.x & 0xFFFF0000u), acc[1]);
    acc[2] = fmaf(a, __uint_as_float(hv.y << 16), acc[2]);
    acc[3] = fmaf(a, __uint_as_float(hv.y & 0xFFFF0000u), acc[3]);
    acc[4] = fmaf(a, __uint_as_float(hv.z << 16), acc[4]);
    acc[5] = fmaf(a, __uint_as_float(hv.z & 0xFFFF0000u), acc[5]);
    acc[6] = fmaf(a, __uint_as_float(hv.w << 16), acc[6]);
    acc[7] = fmaf(a, __uint_as_float(hv.w & 0xFFFF0000u), acc[7]);
}

// ---------------- weight cast: W1[128,128] -> w1t[c][k] bf16 ; W2 -> w2t[c][k]
__global__ __launch_bounds__(256) void cast_w_k(const float* __restrict__ W1,
                                                const float* __restrict__ W2,
                                                ushort* __restrict__ w1t,
                                                ushort* __restrict__ w2t) {
    int tid = blockIdx.x * 256 + threadIdx.x;
    if (tid < 16384) {
        int k = tid >> 7, c = tid & 127;
        w1t[c * 128 + k] = (ushort)f2bf(W1[tid]);
    }
    if (tid < 4096) {
        int k = tid >> 5, c = tid & 31;
        w2t[c * 128 + k] = (ushort)f2bf(W2[tid]);
    }
}

// ---------------- GEMM1 (MFMA): x[N,128]fp32 (cast in-reg) @ W1 -> h[N,128]bf16 + as/ad
// Block: 64 rows, 4 waves x 16 rows. 8 col-tiles, K=128 in 4 steps. No LDS.
__global__ __launch_bounds__(256) void gemm1_mfma(
    const float* __restrict__ x, const ushort* __restrict__ w1t,
    const float* __restrict__ atts, const float* __restrict__ attd,
    ushort* __restrict__ h, float* __restrict__ as_, float* __restrict__ ad_, int N) {
    const int w = threadIdx.x >> 6;
    const int l = threadIdx.x & 63;
    const int c15 = l & 15;
    const int quad = l >> 4;
    const int n_base = blockIdx.x * 64 + w * 16;
    const int n = n_base + c15;

    bf16x8 a[4];
    if (n < N) {
        const float4* xr = (const float4*)(x + (size_t)n * 128);
#pragma unroll
        for (int ks = 0; ks < 4; ks++) {
            float4 p0 = xr[ks * 8 + quad * 2];
            float4 p1 = xr[ks * 8 + quad * 2 + 1];
            uint4 u;
            u.x = f2bf(p0.x) | (f2bf(p0.y) << 16);
            u.y = f2bf(p0.z) | (f2bf(p0.w) << 16);
            u.z = f2bf(p1.x) | (f2bf(p1.y) << 16);
            u.w = f2bf(p1.z) | (f2bf(p1.w) << 16);
            a[ks] = as_bf16x8(u);
        }
    } else {
        uint4 z = make_uint4(0, 0, 0, 0);
#pragma unroll
        for (int ks = 0; ks < 4; ks++) a[ks] = as_bf16x8(z);
    }

    f32x4 acc[8];
#pragma unroll
    for (int ct = 0; ct < 8; ct++) acc[ct] = (f32x4){0.f, 0.f, 0.f, 0.f};

#pragma unroll
    for (int ct = 0; ct < 8; ct++) {
        const uint4* wr = (const uint4*)(w1t + (size_t)(ct * 16 + c15) * 128);
#pragma unroll
        for (int ks = 0; ks < 4; ks++) {
            bf16x8 bfrag = as_bf16x8(wr[ks * 4 + quad]);
            acc[ct] = __builtin_amdgcn_mfma_f32_16x16x32_bf16(a[ks], bfrag, acc[ct], 0, 0, 0);
        }
    }

    // h stores: lane holds col=ct*16+c15, rows n_base+quad*4+reg
#pragma unroll
    for (int ct = 0; ct < 8; ct++) {
        int col = ct * 16 + c15;
#pragma unroll
        for (int reg = 0; reg < 4; reg++) {
            int n_out = n_base + quad * 4 + reg;
            if (n_out < N) h[(size_t)n_out * 128 + col] = (ushort)f2bf(acc[ct][reg]);
        }
    }
    // attention logits per head (cols of head hh live in tiles 2hh, 2hh+1)
#pragma unroll
    for (int hh = 0; hh < 4; hh++) {
        float sA = atts[hh * 32 + c15], sB = atts[hh * 32 + 16 + c15];
        float dA = attd[hh * 32 + c15], dB = attd[hh * 32 + 16 + c15];
#pragma unroll
        for (int reg = 0; reg < 4; reg++) {
            float ps = acc[2 * hh][reg] * sA + acc[2 * hh + 1][reg] * sB;
            float pd = acc[2 * hh][reg] * dA + acc[2 * hh + 1][reg] * dB;
            ps += __shfl_xor(ps, 1); pd += __shfl_xor(pd, 1);
            ps += __shfl_xor(ps, 2); pd += __shfl_xor(pd, 2);
            ps += __shfl_xor(ps, 4); pd += __shfl_xor(pd, 4);
            ps += __shfl_xor(ps, 8); pd += __shfl_xor(pd, 8);
            int n_out = n_base + quad * 4 + reg;
            if (c15 == 0 && n_out < N) { as_[n_out * 4 + hh] = ps; ad_[n_out * 4 + hh] = pd; }
        }
    }
}

// ---------------- GEMM2 (MFMA): o1[N,128]bf16 @ W2 -> h2[N,32]bf16 + as/ad
__global__ __launch_bounds__(256) void gemm2_mfma(
    const ushort* __restrict__ ob, const ushort* __restrict__ w2t,
    const float* __restrict__ atts, const float* __restrict__ attd,
    ushort* __restrict__ h, float* __restrict__ as_, float* __restrict__ ad_, int N) {
    const int w = threadIdx.x >> 6;
    const int l = threadIdx.x & 63;
    const int c15 = l & 15;
    const int quad = l >> 4;
    const int n_base = blockIdx.x * 64 + w * 16;
    const int n = n_base + c15;

    bf16x8 a[4];
    if (n < N) {
        const uint4* xr = (const uint4*)(ob + (size_t)n * 128);
#pragma unroll
        for (int ks = 0; ks < 4; ks++) a[ks] = as_bf16x8(xr[ks * 4 + quad]);
    } else {
        uint4 z = make_uint4(0, 0, 0, 0);
#pragma unroll
        for (int ks = 0; ks < 4; ks++) a[ks] = as_bf16x8(z);
    }

    f32x4 acc[2];
#pragma unroll
    for (int ct = 0; ct < 2; ct++) acc[ct] = (f32x4){0.f, 0.f, 0.f, 0.f};

#pragma unroll
    for (int ct = 0; ct < 2; ct++) {
        const uint4* wr = (const uint4*)(w2t + (size_t)(ct * 16 + c15) * 128);
#pragma unroll
        for (int ks = 0; ks < 4; ks++) {
            bf16x8 bfrag = as_bf16x8(wr[ks * 4 + quad]);
            acc[ct] = __builtin_amdgcn_mfma_f32_16x16x32_bf16(a[ks], bfrag, acc[ct], 0, 0, 0);
        }
    }

#pragma unroll
    for (int ct = 0; ct < 2; ct++) {
        int col = ct * 16 + c15;
#pragma unroll
        for (int reg = 0; reg < 4; reg++) {
            int n_out = n_base + quad * 4 + reg;
            if (n_out < N) h[(size_t)n_out * 32 + col] = (ushort)f2bf(acc[ct][reg]);
        }
    }
    float sA = atts[c15], sB = atts[16 + c15];
    float dA = attd[c15], dB = attd[16 + c15];
#pragma unroll
    for (int reg = 0; reg < 4; reg++) {
        float ps = acc[0][reg] * sA + acc[1][reg] * sB;
        float pd = acc[0][reg] * dA + acc[1][reg] * dB;
        ps += __shfl_xor(ps, 1); pd += __shfl_xor(pd, 1);
        ps += __shfl_xor(ps, 2); pd += __shfl_xor(pd, 2);
        ps += __shfl_xor(ps, 4); pd += __shfl_xor(pd, 4);
        ps += __shfl_xor(ps, 8); pd += __shfl_xor(pd, 8);
        int n_out = n_base + quad * 4 + reg;
        if (c15 == 0 && n_out < N) { as_[n_out] = ps; ad_[n_out] = pd; }
    }
}

// ---------------- CSR build: hist+rank -> scan -> atomic-free scatter -------
__global__ __launch_bounds__(256) void hist_rank_k(const int* __restrict__ ei, int E, int N,
                                                   int* __restrict__ deg, int* __restrict__ rank) {
    int e = blockIdx.x * 256 + threadIdx.x;
    if (e >= E + N) return;
    int d = (e < E) ? ei[E + e] : e - E;
    rank[e] = atomicAdd(&deg[d], 1);
}

__global__ __launch_bounds__(256) void scan1_k(const int* __restrict__ deg,
                                               int* __restrict__ tmp, int* __restrict__ partial, int N) {
    __shared__ int sh[256];
    int i = blockIdx.x * 256 + threadIdx.x;
    int v = (i < N) ? deg[i] : 0;
    sh[threadIdx.x] = v;
    __syncthreads();
#pragma unroll
    for (int off = 1; off < 256; off <<= 1) {
        int t = (threadIdx.x >= off) ? sh[threadIdx.x - off] : 0;
        __syncthreads();
        sh[threadIdx.x] += t;
        __syncthreads();
    }
    if (i < N) tmp[i] = sh[threadIdx.x];
    if (threadIdx.x == 255) partial[blockIdx.x] = sh[255];
}

__global__ __launch_bounds__(1024) void scan2_k(int* __restrict__ partial, int B) {
    __shared__ int sh[1024];
    int i = threadIdx.x;
    int v = (i < B) ? partial[i] : 0;
    sh[i] = v;
    __syncthreads();
#pragma unroll
    for (int off = 1; off < 1024; off <<= 1) {
        int t = (i >= off) ? sh[i - off] : 0;
        __syncthreads();
        sh[i] += t;
        __syncthreads();
    }
    if (i < B) partial[i] = sh[i] - v;   // exclusive
}

__global__ __launch_bounds__(256) void scan3_k(const int* __restrict__ tmp, const int* __restrict__ partial,
                                               int* __restrict__ rs, int N) {
    int i = blockIdx.x * 256 + threadIdx.x;
    if (i < N) rs[i + 1] = tmp[i] + partial[blockIdx.x];
    if (i == 0) rs[0] = 0;
}

__global__ __launch_bounds__(256) void scatter_k(const int* __restrict__ ei, const int* __restrict__ rank,
                                                 const int* __restrict__ rs, int E, int N,
                                                 int* __restrict__ csr) {
    int e = blockIdx.x * 256 + threadIdx.x;
    if (e >= E + N) return;
    int s, d;
    if (e < E) { s = ei[e]; d = ei[E + e]; } else { s = e - E; d = s; }
    csr[rs[d] + rank[e]] = s;      // fire-and-forget random store
}

// ---------------- layer-1 gather (R10): 32 lanes/dst, 8 bf16 ch/lane.
// 16-edge batches: half 0 (lanes 0-15) processes edges [0-7], half 1
// (lanes 16-31) edges [8-15]; each half keeps R8's hv[8] footprint.
// Half h's lanes load slots h*8+sl, h*8+sl+4 (disjoint across halves).
// Cross-half combine (shfl_xor 16) at the end; half 0 writes the output.
__global__ __launch_bounds__(256) void gather1_k(
    const int* __restrict__ rs, const int* __restrict__ csr,
    const float* __restrict__ as_, const float* __restrict__ ad_,
    const uint4* __restrict__ h, const float* __restrict__ b,
    ushort* __restrict__ o, int N) {
    const int jj   = threadIdx.x & 31;
    const int l16  = jj & 15;
    const int sub  = jj & 16;            // half base (0/16) in 32-window
    const int half = jj >> 4;            // 0 or 1
    const int d = blockIdx.x * 8 + (threadIdx.x >> 5);
    if (d >= N) return;
    const int hl = l16 >> 2;             // my head
    const int sl = l16 & 3;              // my slot base within half
    const int soff = half * 8 + sl;      // my slot base within 16-edge batch
    const int beg = rs[d], end = rs[d + 1];
    const float adv = ad_[d * 4 + hl];

    float acc[8];
#pragma unroll
    for (int i = 0; i < 8; i++) acc[i] = 0.f;
    float den = 0.f;

    int j0 = beg;
    int sv0 = 0, sv1 = 0;
    float ex0 = 0.f, ex1 = 0.f;
    bool have = (j0 + 16 <= end);
    if (have) {
        sv0 = csr[j0 + soff];
        sv1 = csr[j0 + soff + 4];
        ex0 = __expf(fminf(lrelu(as_[sv0 * 4 + hl] + adv), 80.f));
        ex1 = __expf(fminf(lrelu(as_[sv1 * 4 + hl] + adv), 80.f));
    }
    while (have) {
        bool nhave = (j0 + 32 <= end);
        int na = nhave ? (j0 + 16) : beg;        // safe addr (deg>=16 here)
        int p0 = csr[na + soff];
        int p1 = csr[na + soff + 4];
        den += ex0 + ex1;                        // disjoint slots across halves
        float av[8]; uint4 hv[8];
#pragma unroll
        for (int e = 0; e < 8; e++) {
            const int k = e >> 2, q = e & 3;
            const int srcl = sub + (l16 & 12) + q;   // source within own half
            float exk = k ? ex1 : ex0;
            int   svk = k ? sv1 : sv0;
            av[e] = __shfl(exk, srcl, 32);
            int s = __shfl(svk, srcl, 32);
            hv[e] = h[(size_t)s * 16 + l16];
        }
        // next-batch as_ + exp: issued after hv so their wait leaves hv in flight
        float q0 = __expf(fminf(lrelu(as_[p0 * 4 + hl] + adv), 80.f));
        float q1 = __expf(fminf(lrelu(as_[p1 * 4 + hl] + adv), 80.f));
#pragma unroll
        for (int e = 0; e < 8; e++) bf16x8_fma(hv[e], av[e], acc);
        sv0 = p0; sv1 = p1; ex0 = q0; ex1 = q1;
        j0 += 16; have = nhave;
    }
    int r = end - j0;                    // 0..15
    if (r > 0) {
        float e0 = 0.f, e1 = 0.f;
        int   s0 = 0,   s1 = 0;
        if (soff < r) {
            s0 = csr[j0 + soff];
            e0 = __expf(fminf(lrelu(as_[s0 * 4 + hl] + adv), 80.f));
            den += e0;
        }
        if (soff + 4 < r) {
            s1 = csr[j0 + soff + 4];
            e1 = __expf(fminf(lrelu(as_[s1 * 4 + hl] + adv), 80.f));
            den += e1;
        }
        float av[8]; uint4 hv[8];
#pragma unroll
        for (int e = 0; e < 8; e++) {
            const int k = e >> 2, q = e & 3;
            const int srcl = sub + (l16 & 12) + q;
            float exk = k ? e1 : e0;
            int   svk = k ? s1 : s0;
            av[e] = __shfl(exk, srcl, 32);              // unguarded: src lanes active
            int s = __shfl(svk, srcl, 32);
            if (half * 8 + e < r) hv[e] = h[(size_t)s * 16 + l16]; // guarded issue
        }
#pragma unroll
        for (int e = 0; e < 8; e++) if (half * 8 + e < r) bf16x8_fma(hv[e], av[e], acc);
    }
    // reduce: quad (slots within half) then cross-half
    den += __shfl_xor(den, 1, 32);
    den += __shfl_xor(den, 2, 32);
    den += __shfl_xor(den, 16, 32);
#pragma unroll
    for (int i = 0; i < 8; i++) acc[i] += __shfl_xor(acc[i], 16, 32);
    if (half == 0) {
        const float rcp = 1.f / (den + 1e-16f);
        float4 b0 = *(const float4*)&b[l16 * 8];
        float4 b1 = *(const float4*)&b[l16 * 8 + 4];
        float v0 = fmaxf(acc[0] * rcp + b0.x, 0.f);
        float v1 = fmaxf(acc[1] * rcp + b0.y, 0.f);
        float v2 = fmaxf(acc[2] * rcp + b0.z, 0.f);
        float v3 = fmaxf(acc[3] * rcp + b0.w, 0.f);
        float v4 = fmaxf(acc[4] * rcp + b1.x, 0.f);
        float v5 = fmaxf(acc[5] * rcp + b1.y, 0.f);
        float v6 = fmaxf(acc[6] * rcp + b1.z, 0.f);
        float v7 = fmaxf(acc[7] * rcp + b1.w, 0.f);
        uint4 pk;
        pk.x = f2bf(v0) | (f2bf(v1) << 16);
        pk.y = f2bf(v2) | (f2bf(v3) << 16);
        pk.z = f2bf(v4) | (f2bf(v5) << 16);
        pk.w = f2bf(v6) | (f2bf(v7) << 16);
        ((uint4*)o)[(size_t)d * 16 + l16] = pk;
    }
}

// ---------------- layer-2 gather (R10): 8 lanes/dst, 8 bf16 ch/lane.
// 16-edge batches: half 0 (lanes g+0..3) edges [0-7], half 1 (g+4..7)
// edges [8-15]. Half h's lanes load slots h*8+l4, h*8+l4+4 (disjoint).
// Cross-half combine (shfl_xor 4); half 0 writes.
__global__ __launch_bounds__(256) void gather2_k(
    const int* __restrict__ rs, const int* __restrict__ csr,
    const float* __restrict__ as_, const float* __restrict__ ad_,
    const uint4* __restrict__ h, const float* __restrict__ b,
    float* __restrict__ o, int N) {
    const int jj   = threadIdx.x & 31;
    const int l4   = jj & 3;
    const int half = (jj >> 2) & 1;
    const int sub8 = jj & 24;            // 8-lane dst-group base in 32-window
    const int d = blockIdx.x * 32 + (threadIdx.x >> 5) * 4 + (jj >> 3);
    if (d >= N) return;
    const int soff = half * 8 + l4;
    const int beg = rs[d], end = rs[d + 1];
    const float adv = ad_[d];

    float acc[8];
#pragma unroll
    for (int i = 0; i < 8; i++) acc[i] = 0.f;
    float den = 0.f;

    int j0 = beg;
    int sv0 = 0, sv1 = 0;
    float ex0 = 0.f, ex1 = 0.f;
    bool have = (j0 + 16 <= end);
    if (have) {
        sv0 = csr[j0 + soff];
        sv1 = csr[j0 + soff + 4];
        ex0 = __expf(fminf(lrelu(as_[sv0] + adv), 80.f));
        ex1 = __expf(fminf(lrelu(as_[sv1] + adv), 80.f));
    }
    while (have) {
        bool nhave = (j0 + 32 <= end);
        int na = nhave ? (j0 + 16) : beg;
        int p0 = csr[na + soff];
        int p1 = csr[na + soff + 4];
        den += ex0 + ex1;
        float av[8]; uint4 hv[8];
#pragma unroll
        for (int e = 0; e < 8; e++) {
            const int k = e >> 2, q = e & 3;
            const int srcl = sub8 + (half << 2) + q;   // source within own half
            float exk = k ? ex1 : ex0;
            int   svk = k ? sv1 : sv0;
            av[e] = __shfl(exk, srcl, 32);
            int s = __shfl(svk, srcl, 32);
            hv[e] = h[(size_t)s * 4 + l4];
        }
        float q0 = __expf(fminf(lrelu(as_[p0] + adv), 80.f));
        float q1 = __expf(fminf(lrelu(as_[p1] + adv), 80.f));
#pragma unroll
        for (int e = 0; e < 8; e++) bf16x8_fma(hv[e], av[e], acc);
        sv0 = p0; sv1 = p1; ex0 = q0; ex1 = q1;
        j0 += 16; have = nhave;
    }
    int r = end - j0;                    // 0..15
    if (r > 0) {
        float e0 = 0.f, e1 = 0.f;
        int   s0 = 0,   s1 = 0;
        if (soff < r) {
            s0 = csr[j0 + soff];
            e0 = __expf(fminf(lrelu(as_[s0] + adv), 80.f));
            den += e0;
        }
        if (soff + 4 < r) {
            s1 = csr[j0 + soff + 4];
            e1 = __expf(fminf(lrelu(as_[s1] + adv), 80.f));
            den += e1;
        }
        float av[8]; uint4 hv[8];
#pragma unroll
        for (int e = 0; e < 8; e++) {
            const int k = e >> 2, q = e & 3;
            const int srcl = sub8 + (half << 2) + q;
            float exk = k ? e1 : e0;
            int   svk = k ? s1 : s0;
            av[e] = __shfl(exk, srcl, 32);              // unguarded
            int s = __shfl(svk, srcl, 32);
            if (half * 8 + e < r) hv[e] = h[(size_t)s * 4 + l4];  // guarded issue
        }
#pragma unroll
        for (int e = 0; e < 8; e++) if (half * 8 + e < r) bf16x8_fma(hv[e], av[e], acc);
    }
    // reduce: quad (slots within half) then cross-half
    den += __shfl_xor(den, 1, 32);
    den += __shfl_xor(den, 2, 32);
    den += __shfl_xor(den, 4, 32);
#pragma unroll
    for (int i = 0; i < 8; i++) acc[i] += __shfl_xor(acc[i], 4, 32);
    if (half == 0) {
        const float rcp = 1.f / (den + 1e-16f);
        float4 b0 = *(const float4*)&b[l4 * 8];
        float4 b1 = *(const float4*)&b[l4 * 8 + 4];
        float4 o0, o1v;
        o0.x  = acc[0] * rcp + b0.x;
        o0.y  = acc[1] * rcp + b0.y;
        o0.z  = acc[2] * rcp + b0.z;
        o0.w  = acc[3] * rcp + b0.w;
        o1v.x = acc[4] * rcp + b1.x;
        o1v.y = acc[5] * rcp + b1.y;
        o1v.z = acc[6] * rcp + b1.z;
        o1v.w = acc[7] * rcp + b1.w;
        *(float4*)&o[(size_t)d * 32 + l4 * 8]     = o0;
        *(float4*)&o[(size_t)d * 32 + l4 * 8 + 4] = o1v;
    }
}

extern "C" void kernel_launch(void* const* d_in, const int* in_sizes, int n_in,
                              void* d_out, int out_size, void* d_ws, size_t ws_size,
                              hipStream_t stream) {
    const float* x    = (const float*)d_in[0];
    const int*   ei   = (const int*)d_in[1];
    const float* W1   = (const float*)d_in[2];
    const float* as1v = (const float*)d_in[3];
    const float* ad1v = (const float*)d_in[4];
    const float* b1   = (const float*)d_in[5];
    const float* W2   = (const float*)d_in[6];
    const float* as2v = (const float*)d_in[7];
    const float* ad2v = (const float*)d_in[8];
    const float* b2   = (const float*)d_in[9];
    float* out = (float*)d_out;

    const int N = in_sizes[0] / 128;
    const int E = in_sizes[1] / 2;
    const int EN = E + N;
    const int B = (N + 255) / 256;   // scan chunks (must be <= 1024)

    // workspace layout
    char* base = (char*)d_ws;
    size_t o = 0;
    auto alloc = [&](size_t bytes) { void* p = base + o; o += (bytes + 255) & ~(size_t)255; return p; };
    ushort* w1t  = (ushort*)alloc((size_t)128 * 128 * 2);
    ushort* w2t  = (ushort*)alloc((size_t)32 * 128 * 2);
    ushort* h1   = (ushort*)alloc((size_t)N * 128 * 2);
    ushort* h2   = (ushort*)alloc((size_t)N * 32 * 2);
    ushort* o1   = (ushort*)alloc((size_t)N * 128 * 2);
    float*  as1  = (float*)alloc((size_t)N * 4 * 4);
    float*  ad1  = (float*)alloc((size_t)N * 4 * 4);
    float*  as2  = (float*)alloc((size_t)N * 4);
    float*  ad2  = (float*)alloc((size_t)N * 4);
    int*    deg  = (int*)alloc((size_t)N * 4);
    int*    tmp  = (int*)alloc((size_t)N * 4);
    int*    part = (int*)alloc((size_t)1024 * 4);
    int*    rs   = (int*)alloc((size_t)(N + 1) * 4);
    int*    rank = (int*)alloc((size_t)EN * 4);
    int*    csr  = (int*)alloc((size_t)EN * 4);

    hipMemsetAsync(deg, 0, (size_t)N * 4, stream);

    const int nbE = (EN + 255) / 256;
    const int nbN = (N + 255) / 256;
    const int nbG = (N + 63) / 64;

    // ---- weight cast + layer-1 GEMM (MFMA, fused x cast) + CSR build
    cast_w_k<<<64, 256, 0, stream>>>(W1, W2, w1t, w2t);
    gemm1_mfma<<<nbG, 256, 0, stream>>>(x, w1t, as1v, ad1v, h1, as1, ad1, N);
    hist_rank_k<<<nbE, 256, 0, stream>>>(ei, E, N, deg, rank);
    scan1_k<<<nbN, 256, 0, stream>>>(deg, tmp, part, N);
    scan2_k<<<1, 1024, 0, stream>>>(part, B);
    scan3_k<<<nbN, 256, 0, stream>>>(tmp, part, rs, N);
    scatter_k<<<nbE, 256, 0, stream>>>(ei, rank, rs, E, N, csr);

    // ---- layer 1 edge softmax + aggregate + bias + relu -> o1 (bf16)
    gather1_k<<<(N + 7) / 8, 256, 0, stream>>>(rs, csr, as1, ad1, (const uint4*)h1, b1, o1, N);

    // ---- layer 2
    gemm2_mfma<<<nbG, 256, 0, stream>>>(o1, w2t, as2v, ad2v, h2, as2, ad2, N);
    gather2_k<<<(N + 31) / 32, 256, 0, stream>>>(rs, csr, as2, ad2, (const uint4*)h2, b2, out, N);
}

// Round 5
// 347.321 us; speedup vs baseline: 1.0981x; 1.0896x over previous
//
#include <hip/hip_runtime.h>
#include <hip/hip_bf16.h>

// GAT 2-layer. N=100000, L1: H=4,C=32 (HC=128), L2: H=1,C=32.
//
// R1: CSR gather instead of float-atomic scatter (1588 -> 826 us).
// R2: cooperative softmax via shfl broadcast (826 -> 734).
// R3: single-pass softmax, float4 loads, 8-deep unroll (734 -> 595).
// R4: atomic-free scatter; bf16 h payload; 16-deep unroll (595 -> 491).
// R5: both GEMMs -> bf16 MFMA 16x16x32, zero LDS/barriers (491 -> 443).
// R6: FAILED launch_bounds(256,8) -> scratch spills. Reverted.
// R7: gather1 = R4-exact body; gemm2 casts o1 fp32->bf16 in-register (~408).
// R8: two-phase 8-edge batches, hv[8] in flight, bf16 o1 (408 -> 363;
//     gather1 107 -> 75; VGPR 48, occ 47.5%).
// R9: FAILED hv[16]: VGPR 84 -> occ 28%, gather1 83.7. TLP loss > MLP gain.
// R10: FAILED 32 lanes/dst halves: occ 37.6%, VALU 43%, gather1 81.
//     Lesson: R8's gather body is the local optimum; stop re-rolling it.
// R11: keep R8 gather loops EXACTLY; attack dispatch count instead.
//     (a) hist_rank fused into gemm1 as extra blocks (independent work,
//         overlaps atomics with MFMA; one dispatch removed).
//     (b) gemm2 fused into gather1 epilogue: block's 16 dsts = one MFMA
//         tile; o1 rows staged in 4.6KB LDS; wave 0 runs the 8-MFMA gemm2
//         + logit reduce. Removes gemm2 dispatch AND o1 51MB round-trip.
//     Tail-guarded hv loads kept from R9/R10 (FETCH 241->232, harmless).
// Self-loops are implicit: edge ids >= E map to (n,n).

typedef __bf16 bf16x8 __attribute__((ext_vector_type(8)));
typedef float f32x4 __attribute__((ext_vector_type(4)));

__device__ __forceinline__ float lrelu(float v) { return v >= 0.f ? v : 0.2f * v; }

__device__ __forceinline__ unsigned f2bf(float f) {   // RTNE f32->bf16 (finite inputs)
    unsigned u = __float_as_uint(f);
    return (u + 0x7FFFu + ((u >> 16) & 1u)) >> 16;
}

__device__ __forceinline__ bf16x8 as_bf16x8(uint4 u) {
    union { uint4 u; bf16x8 b; } c; c.u = u; return c.b;
}

__device__ __forceinline__ void bf16x8_fma(uint4 hv, float a, float* acc) {
    acc[0] = fmaf(a, __uint_as_float(hv.x << 16), acc[0]);
    acc[1] = fmaf(a, __uint_as_float(hv.x & 0xFFFF0000u), acc[1]);
    acc[2] = fmaf(a, __uint_as_float(hv.y << 16), acc[2]);
    acc[3] = fmaf(a, __uint_as_float(hv.y & 0xFFFF0000u), acc[3]);
    acc[4] = fmaf(a, __uint_as_float(hv.z << 16), acc[4]);
    acc[5] = fmaf(a, __uint_as_float(hv.z & 0xFFFF0000u), acc[5]);
    acc[6] = fmaf(a, __uint_as_float(hv.w << 16), acc[6]);
    acc[7] = fmaf(a, __uint_as_float(hv.w & 0xFFFF0000u), acc[7]);
}

// ---------------- weight cast: W1[128,128] -> w1t[c][k] bf16 ; W2 -> w2t[c][k]
__global__ __launch_bounds__(256) void cast_w_k(const float* __restrict__ W1,
                                                const float* __restrict__ W2,
                                                ushort* __restrict__ w1t,
                                                ushort* __restrict__ w2t) {
    int tid = blockIdx.x * 256 + threadIdx.x;
    if (tid < 16384) {
        int k = tid >> 7, c = tid & 127;
        w1t[c * 128 + k] = (ushort)f2bf(W1[tid]);
    }
    if (tid < 4096) {
        int k = tid >> 5, c = tid & 31;
        w2t[c * 128 + k] = (ushort)f2bf(W2[tid]);
    }
}

// ---------------- GEMM1 (MFMA) + fused edge histogram.
// Blocks [0, nbG): x[N,128]fp32 (cast in-reg) @ W1 -> h[N,128]bf16 + as/ad.
// Blocks [nbG, nbG+nbE): hist_rank for edge e (independent work; overlaps
// the latency-bound atomics with the MFMA blocks on the same dispatch).
__global__ __launch_bounds__(256) void gemm1_hist_k(
    const float* __restrict__ x, const ushort* __restrict__ w1t,
    const float* __restrict__ atts, const float* __restrict__ attd,
    ushort* __restrict__ h, float* __restrict__ as_, float* __restrict__ ad_,
    const int* __restrict__ ei, int* __restrict__ deg, int* __restrict__ rank,
    int N, int E, int nbG) {
    if (blockIdx.x >= nbG) {               // ---- histogram path
        int e = (blockIdx.x - nbG) * 256 + threadIdx.x;
        if (e < E + N) {
            int d = (e < E) ? ei[E + e] : e - E;
            rank[e] = atomicAdd(&deg[d], 1);
        }
        return;
    }
    // ---- GEMM path (R5 body, unchanged)
    const int w = threadIdx.x >> 6;
    const int l = threadIdx.x & 63;
    const int c15 = l & 15;
    const int quad = l >> 4;
    const int n_base = blockIdx.x * 64 + w * 16;
    const int n = n_base + c15;

    bf16x8 a[4];
    if (n < N) {
        const float4* xr = (const float4*)(x + (size_t)n * 128);
#pragma unroll
        for (int ks = 0; ks < 4; ks++) {
            float4 p0 = xr[ks * 8 + quad * 2];
            float4 p1 = xr[ks * 8 + quad * 2 + 1];
            uint4 u;
            u.x = f2bf(p0.x) | (f2bf(p0.y) << 16);
            u.y = f2bf(p0.z) | (f2bf(p0.w) << 16);
            u.z = f2bf(p1.x) | (f2bf(p1.y) << 16);
            u.w = f2bf(p1.z) | (f2bf(p1.w) << 16);
            a[ks] = as_bf16x8(u);
        }
    } else {
        uint4 z = make_uint4(0, 0, 0, 0);
#pragma unroll
        for (int ks = 0; ks < 4; ks++) a[ks] = as_bf16x8(z);
    }

    f32x4 acc[8];
#pragma unroll
    for (int ct = 0; ct < 8; ct++) acc[ct] = (f32x4){0.f, 0.f, 0.f, 0.f};

#pragma unroll
    for (int ct = 0; ct < 8; ct++) {
        const uint4* wr = (const uint4*)(w1t + (size_t)(ct * 16 + c15) * 128);
#pragma unroll
        for (int ks = 0; ks < 4; ks++) {
            bf16x8 bfrag = as_bf16x8(wr[ks * 4 + quad]);
            acc[ct] = __builtin_amdgcn_mfma_f32_16x16x32_bf16(a[ks], bfrag, acc[ct], 0, 0, 0);
        }
    }

#pragma unroll
    for (int ct = 0; ct < 8; ct++) {
        int col = ct * 16 + c15;
#pragma unroll
        for (int reg = 0; reg < 4; reg++) {
            int n_out = n_base + quad * 4 + reg;
            if (n_out < N) h[(size_t)n_out * 128 + col] = (ushort)f2bf(acc[ct][reg]);
        }
    }
#pragma unroll
    for (int hh = 0; hh < 4; hh++) {
        float sA = atts[hh * 32 + c15], sB = atts[hh * 32 + 16 + c15];
        float dA = attd[hh * 32 + c15], dB = attd[hh * 32 + 16 + c15];
#pragma unroll
        for (int reg = 0; reg < 4; reg++) {
            float ps = acc[2 * hh][reg] * sA + acc[2 * hh + 1][reg] * sB;
            float pd = acc[2 * hh][reg] * dA + acc[2 * hh + 1][reg] * dB;
            ps += __shfl_xor(ps, 1); pd += __shfl_xor(pd, 1);
            ps += __shfl_xor(ps, 2); pd += __shfl_xor(pd, 2);
            ps += __shfl_xor(ps, 4); pd += __shfl_xor(pd, 4);
            ps += __shfl_xor(ps, 8); pd += __shfl_xor(pd, 8);
            int n_out = n_base + quad * 4 + reg;
            if (c15 == 0 && n_out < N) { as_[n_out * 4 + hh] = ps; ad_[n_out * 4 + hh] = pd; }
        }
    }
}

// ---------------- CSR build: scan -> atomic-free scatter ---------------------
__global__ __launch_bounds__(256) void scan1_k(const int* __restrict__ deg,
                                               int* __restrict__ tmp, int* __restrict__ partial, int N) {
    __shared__ int sh[256];
    int i = blockIdx.x * 256 + threadIdx.x;
    int v = (i < N) ? deg[i] : 0;
    sh[threadIdx.x] = v;
    __syncthreads();
#pragma unroll
    for (int off = 1; off < 256; off <<= 1) {
        int t = (threadIdx.x >= off) ? sh[threadIdx.x - off] : 0;
        __syncthreads();
        sh[threadIdx.x] += t;
        __syncthreads();
    }
    if (i < N) tmp[i] = sh[threadIdx.x];
    if (threadIdx.x == 255) partial[blockIdx.x] = sh[255];
}

__global__ __launch_bounds__(1024) void scan2_k(int* __restrict__ partial, int B) {
    __shared__ int sh[1024];
    int i = threadIdx.x;
    int v = (i < B) ? partial[i] : 0;
    sh[i] = v;
    __syncthreads();
#pragma unroll
    for (int off = 1; off < 1024; off <<= 1) {
        int t = (i >= off) ? sh[i - off] : 0;
        __syncthreads();
        sh[i] += t;
        __syncthreads();
    }
    if (i < B) partial[i] = sh[i] - v;   // exclusive
}

__global__ __launch_bounds__(256) void scan3_k(const int* __restrict__ tmp, const int* __restrict__ partial,
                                               int* __restrict__ rs, int N) {
    int i = blockIdx.x * 256 + threadIdx.x;
    if (i < N) rs[i + 1] = tmp[i] + partial[blockIdx.x];
    if (i == 0) rs[0] = 0;
}

__global__ __launch_bounds__(256) void scatter_k(const int* __restrict__ ei, const int* __restrict__ rank,
                                                 const int* __restrict__ rs, int E, int N,
                                                 int* __restrict__ csr) {
    int e = blockIdx.x * 256 + threadIdx.x;
    if (e >= E + N) return;
    int s, d;
    if (e < E) { s = ei[e]; d = ei[E + e]; } else { s = e - E; d = s; }
    csr[rs[d] + rank[e]] = s;      // fire-and-forget random store
}

// ---------------- layer-1 gather (R8 loop) + fused GEMM2 epilogue.
// 16 lanes/dst, 8 bf16 ch/lane, two-phase 8-edge batches (R8-exact).
// Epilogue: pack o1 row to LDS (16 dsts x 16 uint4, padded), barrier,
// wave 0 runs gemm2 (8 MFMAs) + att-logit reduce for the block's 16 rows.
// No early return (barrier); d>=N lanes run an empty loop.
__global__ __launch_bounds__(256) void gather1_k(
    const int* __restrict__ rs, const int* __restrict__ csr,
    const float* __restrict__ as_, const float* __restrict__ ad_,
    const uint4* __restrict__ h, const float* __restrict__ b,
    const ushort* __restrict__ w2t, const float* __restrict__ atts2,
    const float* __restrict__ attd2,
    ushort* __restrict__ h2, float* __restrict__ as2, float* __restrict__ ad2,
    int N) {
    __shared__ uint4 o1s[16][18];        // [dst_local][ch-slot], +2 pad vs bank conflicts
    const int jj = threadIdx.x & 31;
    const int l16 = jj & 15;
    const int sub = jj & 16;             // 16-lane subgroup base in 32-window
    const int dl = (threadIdx.x >> 5) * 2 + (jj >> 4);   // 0..15
    const int d = blockIdx.x * 16 + dl;
    const int hl = l16 >> 2;             // my head
    const int sl = l16 & 3;              // my slot base
    int beg = 0, end = 0;
    float adv = 0.f;
    if (d < N) { beg = rs[d]; end = rs[d + 1]; adv = ad_[d * 4 + hl]; }

    float acc[8];
#pragma unroll
    for (int i = 0; i < 8; i++) acc[i] = 0.f;
    float den = 0.f;

    int j0 = beg;
    int sv0 = 0, sv1 = 0;
    float ex0 = 0.f, ex1 = 0.f;
    bool have = (j0 + 8 <= end);
    if (have) {
        sv0 = csr[j0 + sl];
        sv1 = csr[j0 + sl + 4];
        ex0 = __expf(fminf(lrelu(as_[sv0 * 4 + hl] + adv), 80.f));
        ex1 = __expf(fminf(lrelu(as_[sv1 * 4 + hl] + adv), 80.f));
    }
    while (have) {
        bool nhave = (j0 + 16 <= end);
        int na = nhave ? (j0 + 8) : beg;          // safe addr (deg>=8 here)
        int psv0 = csr[na + sl];
        int psv1 = csr[na + sl + 4];
        den += ex0 + ex1;
        float av[8]; uint4 hv[8];
#pragma unroll
        for (int e = 0; e < 8; e++) {
            const int k = e >> 2, q = e & 3;
            const int srcl = sub + (l16 & 12) + q;
            float exk = k ? ex1 : ex0;
            int   svk = k ? sv1 : sv0;
            av[e] = __shfl(exk, srcl, 32);
            int s = __shfl(svk, srcl, 32);
            hv[e] = h[(size_t)s * 16 + l16];
        }
        // next-chunk as_ loads: issued after hv so their wait leaves hv in flight
        float pex0 = __expf(fminf(lrelu(as_[psv0 * 4 + hl] + adv), 80.f));
        float pex1 = __expf(fminf(lrelu(as_[psv1 * 4 + hl] + adv), 80.f));
#pragma unroll
        for (int e = 0; e < 8; e++) bf16x8_fma(hv[e], av[e], acc);
        sv0 = psv0; sv1 = psv1; ex0 = pex0; ex1 = pex1;
        j0 += 8; have = nhave;
    }
    int r = end - j0;                    // 0..7
    if (r > 0) {
        float ex0r = 0.f, ex1r = 0.f;
        int   sv0r = 0,   sv1r = 0;
        if (sl < r) {
            sv0r = csr[j0 + sl];
            ex0r = __expf(fminf(lrelu(as_[sv0r * 4 + hl] + adv), 80.f));
            den += ex0r;
        }
        if (sl + 4 < r) {
            sv1r = csr[j0 + sl + 4];
            ex1r = __expf(fminf(lrelu(as_[sv1r * 4 + hl] + adv), 80.f));
            den += ex1r;
        }
        float av[8]; uint4 hv[8];
#pragma unroll
        for (int e = 0; e < 8; e++) {
            const int k = e >> 2, q = e & 3;
            const int srcl = sub + (l16 & 12) + q;
            float exk = k ? ex1r : ex0r;
            int   svk = k ? sv1r : sv0r;
            av[e] = __shfl(exk, srcl, 32);              // unguarded: src lanes active
            int s = __shfl(svk, srcl, 32);
            if (e < r) hv[e] = h[(size_t)s * 16 + l16]; // guarded: no garbage fetch
        }
#pragma unroll
        for (int e = 0; e < 8; e++) if (e < r) bf16x8_fma(hv[e], av[e], acc);
    }
    den += __shfl_xor(den, 1, 32);
    den += __shfl_xor(den, 2, 32);
    const float rcp = 1.f / (den + 1e-16f);
    float4 b0 = *(const float4*)&b[l16 * 8];
    float4 b1 = *(const float4*)&b[l16 * 8 + 4];
    float v0 = fmaxf(acc[0] * rcp + b0.x, 0.f);
    float v1 = fmaxf(acc[1] * rcp + b0.y, 0.f);
    float v2 = fmaxf(acc[2] * rcp + b0.z, 0.f);
    float v3 = fmaxf(acc[3] * rcp + b0.w, 0.f);
    float v4 = fmaxf(acc[4] * rcp + b1.x, 0.f);
    float v5 = fmaxf(acc[5] * rcp + b1.y, 0.f);
    float v6 = fmaxf(acc[6] * rcp + b1.z, 0.f);
    float v7 = fmaxf(acc[7] * rcp + b1.w, 0.f);
    uint4 pk;
    pk.x = f2bf(v0) | (f2bf(v1) << 16);
    pk.y = f2bf(v2) | (f2bf(v3) << 16);
    pk.z = f2bf(v4) | (f2bf(v5) << 16);
    pk.w = f2bf(v6) | (f2bf(v7) << 16);
    o1s[dl][l16] = pk;                   // o1 never touches global memory
    __syncthreads();

    // ---- fused GEMM2: wave 0 computes h2/as2/ad2 for the block's 16 rows
    if (threadIdx.x < 64) {
        const int l = threadIdx.x;
        const int c15g = l & 15;
        const int quad = l >> 4;
        bf16x8 a2[4];
#pragma unroll
        for (int ks = 0; ks < 4; ks++) a2[ks] = as_bf16x8(o1s[c15g][ks * 4 + quad]);
        f32x4 acc2[2];
#pragma unroll
        for (int ct = 0; ct < 2; ct++) acc2[ct] = (f32x4){0.f, 0.f, 0.f, 0.f};
#pragma unroll
        for (int ct = 0; ct < 2; ct++) {
            const uint4* wr = (const uint4*)(w2t + (size_t)(ct * 16 + c15g) * 128);
#pragma unroll
            for (int ks = 0; ks < 4; ks++) {
                bf16x8 bfrag = as_bf16x8(wr[ks * 4 + quad]);
                acc2[ct] = __builtin_amdgcn_mfma_f32_16x16x32_bf16(a2[ks], bfrag, acc2[ct], 0, 0, 0);
            }
        }
        const int nb = blockIdx.x * 16;
#pragma unroll
        for (int ct = 0; ct < 2; ct++) {
            int col = ct * 16 + c15g;
#pragma unroll
            for (int reg = 0; reg < 4; reg++) {
                int n_out = nb + quad * 4 + reg;
                if (n_out < N) h2[(size_t)n_out * 32 + col] = (ushort)f2bf(acc2[ct][reg]);
            }
        }
        float sA = atts2[c15g], sB = atts2[16 + c15g];
        float dA = attd2[c15g], dB = attd2[16 + c15g];
#pragma unroll
        for (int reg = 0; reg < 4; reg++) {
            float ps = acc2[0][reg] * sA + acc2[1][reg] * sB;
            float pd = acc2[0][reg] * dA + acc2[1][reg] * dB;
            ps += __shfl_xor(ps, 1); pd += __shfl_xor(pd, 1);
            ps += __shfl_xor(ps, 2); pd += __shfl_xor(pd, 2);
            ps += __shfl_xor(ps, 4); pd += __shfl_xor(pd, 4);
            ps += __shfl_xor(ps, 8); pd += __shfl_xor(pd, 8);
            int n_out = nb + quad * 4 + reg;
            if (c15g == 0 && n_out < N) { as2[n_out] = ps; ad2[n_out] = pd; }
        }
    }
}

// ---------------- layer-2 gather (R8-exact): 4 lanes/dst, 8 bf16 ch/lane.
__global__ __launch_bounds__(256) void gather2_k(
    const int* __restrict__ rs, const int* __restrict__ csr,
    const float* __restrict__ as_, const float* __restrict__ ad_,
    const uint4* __restrict__ h, const float* __restrict__ b,
    float* __restrict__ o, int N) {
    const int jj = threadIdx.x & 31;
    const int l4 = jj & 3;
    const int sub = jj & 28;             // 4-lane subgroup base
    const int d = blockIdx.x * 64 + (threadIdx.x >> 5) * 8 + (jj >> 2);
    if (d >= N) return;
    const int beg = rs[d], end = rs[d + 1];
    const float adv = ad_[d];

    float acc[8];
#pragma unroll
    for (int i = 0; i < 8; i++) acc[i] = 0.f;
    float den = 0.f;

    int j0 = beg;
    int sv0 = 0, sv1 = 0;
    float ex0 = 0.f, ex1 = 0.f;
    bool have = (j0 + 8 <= end);
    if (have) {
        sv0 = csr[j0 + l4];
        sv1 = csr[j0 + l4 + 4];
        ex0 = __expf(fminf(lrelu(as_[sv0] + adv), 80.f));
        ex1 = __expf(fminf(lrelu(as_[sv1] + adv), 80.f));
    }
    while (have) {
        bool nhave = (j0 + 16 <= end);
        int na = nhave ? (j0 + 8) : beg;
        int psv0 = csr[na + l4];
        int psv1 = csr[na + l4 + 4];
        den += ex0 + ex1;
        float av[8]; uint4 hv[8];
#pragma unroll
        for (int e = 0; e < 8; e++) {
            const int k = e >> 2, q = e & 3;
            const int srcl = sub + q;
            float exk = k ? ex1 : ex0;
            int   svk = k ? sv1 : sv0;
            av[e] = __shfl(exk, srcl, 32);
            int s = __shfl(svk, srcl, 32);
            hv[e] = h[(size_t)s * 4 + l4];
        }
        float pex0 = __expf(fminf(lrelu(as_[psv0] + adv), 80.f));
        float pex1 = __expf(fminf(lrelu(as_[psv1] + adv), 80.f));
#pragma unroll
        for (int e = 0; e < 8; e++) bf16x8_fma(hv[e], av[e], acc);
        sv0 = psv0; sv1 = psv1; ex0 = pex0; ex1 = pex1;
        j0 += 8; have = nhave;
    }
    int r = end - j0;                    // 0..7
    if (r > 0) {
        float ex0r = 0.f, ex1r = 0.f;
        int   sv0r = 0,   sv1r = 0;
        if (l4 < r) {
            sv0r = csr[j0 + l4];
            ex0r = __expf(fminf(lrelu(as_[sv0r] + adv), 80.f));
            den += ex0r;
        }
        if (l4 + 4 < r) {
            sv1r = csr[j0 + l4 + 4];
            ex1r = __expf(fminf(lrelu(as_[sv1r] + adv), 80.f));
            den += ex1r;
        }
        float av[8]; uint4 hv[8];
#pragma unroll
        for (int e = 0; e < 8; e++) {
            const int k = e >> 2, q = e & 3;
            const int srcl = sub + q;
            float exk = k ? ex1r : ex0r;
            int   svk = k ? sv1r : sv0r;
            av[e] = __shfl(exk, srcl, 32);              // unguarded
            int s = __shfl(svk, srcl, 32);
            if (e < r) hv[e] = h[(size_t)s * 4 + l4];   // guarded issue
        }
#pragma unroll
        for (int e = 0; e < 8; e++) if (e < r) bf16x8_fma(hv[e], av[e], acc);
    }
    den += __shfl_xor(den, 1, 32);
    den += __shfl_xor(den, 2, 32);
    const float rcp = 1.f / (den + 1e-16f);
    float4 b0 = *(const float4*)&b[l4 * 8];
    float4 b1 = *(const float4*)&b[l4 * 8 + 4];
    float4 o0, o1v;
    o0.x  = acc[0] * rcp + b0.x;
    o0.y  = acc[1] * rcp + b0.y;
    o0.z  = acc[2] * rcp + b0.z;
    o0.w  = acc[3] * rcp + b0.w;
    o1v.x = acc[4] * rcp + b1.x;
    o1v.y = acc[5] * rcp + b1.y;
    o1v.z = acc[6] * rcp + b1.z;
    o1v.w = acc[7] * rcp + b1.w;
    *(float4*)&o[(size_t)d * 32 + l4 * 8]     = o0;
    *(float4*)&o[(size_t)d * 32 + l4 * 8 + 4] = o1v;
}

extern "C" void kernel_launch(void* const* d_in, const int* in_sizes, int n_in,
                              void* d_out, int out_size, void* d_ws, size_t ws_size,
                              hipStream_t stream) {
    const float* x    = (const float*)d_in[0];
    const int*   ei   = (const int*)d_in[1];
    const float* W1   = (const float*)d_in[2];
    const float* as1v = (const float*)d_in[3];
    const float* ad1v = (const float*)d_in[4];
    const float* b1   = (const float*)d_in[5];
    const float* W2   = (const float*)d_in[6];
    const float* as2v = (const float*)d_in[7];
    const float* ad2v = (const float*)d_in[8];
    const float* b2   = (const float*)d_in[9];
    float* out = (float*)d_out;

    const int N = in_sizes[0] / 128;
    const int E = in_sizes[1] / 2;
    const int EN = E + N;
    const int B = (N + 255) / 256;   // scan chunks (must be <= 1024)

    // workspace layout
    char* base = (char*)d_ws;
    size_t o = 0;
    auto alloc = [&](size_t bytes) { void* p = base + o; o += (bytes + 255) & ~(size_t)255; return p; };
    ushort* w1t  = (ushort*)alloc((size_t)128 * 128 * 2);
    ushort* w2t  = (ushort*)alloc((size_t)32 * 128 * 2);
    ushort* h1   = (ushort*)alloc((size_t)N * 128 * 2);
    ushort* h2   = (ushort*)alloc((size_t)N * 32 * 2);
    float*  as1  = (float*)alloc((size_t)N * 4 * 4);
    float*  ad1  = (float*)alloc((size_t)N * 4 * 4);
    float*  as2  = (float*)alloc((size_t)N * 4);
    float*  ad2  = (float*)alloc((size_t)N * 4);
    int*    deg  = (int*)alloc((size_t)N * 4);
    int*    tmp  = (int*)alloc((size_t)N * 4);
    int*    part = (int*)alloc((size_t)1024 * 4);
    int*    rs   = (int*)alloc((size_t)(N + 1) * 4);
    int*    rank = (int*)alloc((size_t)EN * 4);
    int*    csr  = (int*)alloc((size_t)EN * 4);

    hipMemsetAsync(deg, 0, (size_t)N * 4, stream);

    const int nbE = (EN + 255) / 256;
    const int nbN = (N + 255) / 256;
    const int nbG = (N + 63) / 64;

    // ---- weight cast, then fused [layer-1 GEMM + edge histogram]
    cast_w_k<<<64, 256, 0, stream>>>(W1, W2, w1t, w2t);
    gemm1_hist_k<<<nbG + nbE, 256, 0, stream>>>(x, w1t, as1v, ad1v, h1, as1, ad1,
                                                ei, deg, rank, N, E, nbG);
    scan1_k<<<nbN, 256, 0, stream>>>(deg, tmp, part, N);
    scan2_k<<<1, 1024, 0, stream>>>(part, B);
    scan3_k<<<nbN, 256, 0, stream>>>(tmp, part, rs, N);
    scatter_k<<<nbE, 256, 0, stream>>>(ei, rank, rs, E, N, csr);

    // ---- layer 1 edge softmax + aggregate + bias + relu + fused GEMM2
    gather1_k<<<(N + 15) / 16, 256, 0, stream>>>(rs, csr, as1, ad1, (const uint4*)h1, b1,
                                                 w2t, as2v, ad2v, h2, as2, ad2, N);

    // ---- layer 2 gather
    gather2_k<<<(N + 63) / 64, 256, 0, stream>>>(rs, csr, as2, ad2, (const uint4*)h2, b2, out, N);
}